// Round 8
// baseline (368.924 us; speedup 1.0000x reference)
//
#include <hip/hip_runtime.h>
#include <hip/hip_fp16.h>
#include <math.h>

#define N_NODES 50000
#define N_EDGES 800000
#define N_GRAPHS 64
#define NEG_SLOPE 0.2f
#define SLOTS 64        // bucket capacity; P(in-degree>64) ~ 1e-20 for Poisson(16)

// ---- multisplit fill parameters ----
#define BIN_NODES 256                   // nodes per dst-range bin
#define NBINS 196                       // ceil(50000/256)
#define CAP 6144                        // u32 slots per bin (mean 4082, sigma ~64)
#define P1_BLOCKS 192                   // pass-1 blocks fused ahead of gemm0
#define BATCH 2048                      // edges per block-batch (8 per thread)

typedef _Float16 f16x8 __attribute__((ext_vector_type(8)));
typedef float f32x4 __attribute__((ext_vector_type(4)));

__device__ __forceinline__ float leaky(float x) {
    return x > 0.f ? x : NEG_SLOPE * x;
}

// ------- prep: W -> MFMA lane-major fp16 fragments; zero bin_cursor + d_out -------
__global__ __launch_bounds__(256) void prep_kernel(const float* __restrict__ W0,
                                                   const float* __restrict__ W1,
                                                   const float* __restrict__ W2,
                                                   _Float16* __restrict__ Wt0,
                                                   _Float16* __restrict__ Wt1,
                                                   _Float16* __restrict__ Wt2,
                                                   unsigned int* __restrict__ bin_cursor,
                                                   float* __restrict__ dout, int osz) {
    const int t = blockIdx.x * 256 + threadIdx.x;
    if (t < NBINS) bin_cursor[t] = 0;
    if (t < osz) dout[t] = 0.f;
    const float* W;
    _Float16* Wt;
    int g, CTl, DOUTl;
    if (t < 2048) { W = W0; Wt = Wt0; g = t; CTl = 8; DOUTl = 128; }
    else if (t < 4096) { W = W1; Wt = Wt1; g = t - 2048; CTl = 8; DOUTl = 128; }
    else if (t < 5120) { W = W2; Wt = Wt2; g = t - 4096; CTl = 4; DOUTl = 64; }
    else return;
    const int kt = g / (CTl * 64);
    const int rem = g % (CTl * 64);
    const int ct = rem / 64;
    const int lane = rem % 64;
    const int kbase = kt * 32 + (lane >> 4) * 8;
    const int c = ct * 16 + (lane & 15);
#pragma unroll
    for (int b = 0; b < 8; ++b)
        Wt[(size_t)g * 8 + b] = (_Float16)W[(size_t)(kbase + b) * DOUTl + c];
}

// ------- MFMA GEMM body: Hs(fp16, SLICE-MAJOR) = X @ W; as_/ad_ alphas -------
// Hs layout: [slice=col>>5][node][col&31] — 32-channel slices, 64B rows (R7: sliced
// gather's per-XCD working set 3.2MB fits the 4MB L2; FETCH confirmed 95->41MB).
template <int DOUT, typename XT>
__device__ __forceinline__ void mfma_gemm_body(const XT* __restrict__ X,
                                               const _Float16* __restrict__ Wt,
                                               const float* __restrict__ a_src,
                                               const float* __restrict__ a_dst,
                                               _Float16* __restrict__ Hs,
                                               float* __restrict__ as_,
                                               float* __restrict__ ad_, int N, int bid,
                                               _Float16* xs) {
    constexpr int CT = DOUT / 16;
    const int tid = threadIdx.x;
    const int n0 = bid * 64;

    if constexpr (sizeof(XT) == 4) {
        const float4* X4 = reinterpret_cast<const float4*>(X);
        for (int idx = tid; idx < 64 * 16; idx += 256) {
            const int r = idx >> 4, q = idx & 15;
            const int n = n0 + r;
            float4 v0 = make_float4(0.f, 0.f, 0.f, 0.f), v1 = v0;
            if (n < N) {
                v0 = X4[(size_t)n * 32 + 2 * q];
                v1 = X4[(size_t)n * 32 + 2 * q + 1];
            }
            f16x8 hv;
            hv[0] = (_Float16)v0.x; hv[1] = (_Float16)v0.y;
            hv[2] = (_Float16)v0.z; hv[3] = (_Float16)v0.w;
            hv[4] = (_Float16)v1.x; hv[5] = (_Float16)v1.y;
            hv[6] = (_Float16)v1.z; hv[7] = (_Float16)v1.w;
            *reinterpret_cast<f16x8*>(&xs[r * 128 + ((q ^ (r & 15)) << 3)]) = hv;
        }
    } else {
        const f16x8* X8 = reinterpret_cast<const f16x8*>(X);
        for (int idx = tid; idx < 64 * 16; idx += 256) {
            const int r = idx >> 4, q = idx & 15;
            const int n = n0 + r;
            f16x8 hv = {};
            if (n < N) hv = X8[(size_t)n * 16 + q];
            *reinterpret_cast<f16x8*>(&xs[r * 128 + ((q ^ (r & 15)) << 3)]) = hv;
        }
    }
    __syncthreads();

    const int wave = tid >> 6, lane = tid & 63;
    const int colb = lane & 15;
    const int kg = lane >> 4;
    const int arow = wave * 16 + colb;

    f32x4 acc[CT];
#pragma unroll
    for (int ct = 0; ct < CT; ++ct) {
        acc[ct][0] = 0.f; acc[ct][1] = 0.f; acc[ct][2] = 0.f; acc[ct][3] = 0.f;
    }
    const f16x8* Wt8 = reinterpret_cast<const f16x8*>(Wt);
#pragma unroll
    for (int kt = 0; kt < 4; ++kt) {
        f16x8 A = *reinterpret_cast<const f16x8*>(
            &xs[arow * 128 + (((kt * 4 + kg) ^ (arow & 15)) << 3)]);
#pragma unroll
        for (int ct = 0; ct < CT; ++ct) {
            f16x8 B = Wt8[(kt * CT + ct) * 64 + lane];
            acc[ct] = __builtin_amdgcn_mfma_f32_16x16x32_f16(A, B, acc[ct], 0, 0, 0);
        }
    }

    float ps[4] = {0.f, 0.f, 0.f, 0.f}, pd[4] = {0.f, 0.f, 0.f, 0.f};
#pragma unroll
    for (int ct = 0; ct < CT; ++ct) {
        const int col = ct * 16 + colb;
        const float asv = a_src[col];
        const float adv = a_dst[col];
        const size_t sbase = (size_t)(col >> 5) * N * 32 + (col & 31);
#pragma unroll
        for (int r = 0; r < 4; ++r) {
            const float d = acc[ct][r];
            ps[r] += d * asv;
            pd[r] += d * adv;
            const int row = n0 + wave * 16 + kg * 4 + r;
            if (row < N) Hs[sbase + (size_t)row * 32] = (_Float16)d;
        }
    }
#pragma unroll
    for (int off = 1; off < 16; off <<= 1) {
#pragma unroll
        for (int r = 0; r < 4; ++r) {
            ps[r] += __shfl_xor(ps[r], off, 64);
            pd[r] += __shfl_xor(pd[r], off, 64);
        }
    }
    if (colb == 0) {
#pragma unroll
        for (int r = 0; r < 4; ++r) {
            const int row = n0 + wave * 16 + kg * 4 + r;
            if (row < N) {
                as_[row] = ps[r];
                ad_[row] = pd[r];
            }
        }
    }
}

template <int DOUT, typename XT>
__global__ __launch_bounds__(256) void mfma_gemm_kernel(const XT* __restrict__ X,
                                                        const _Float16* __restrict__ Wt,
                                                        const float* __restrict__ a_src,
                                                        const float* __restrict__ a_dst,
                                                        _Float16* __restrict__ Hs,
                                                        float* __restrict__ as_,
                                                        float* __restrict__ ad_, int N) {
    __shared__ __align__(16) _Float16 xs[64 * 128];
    mfma_gemm_body<DOUT, XT>(X, Wt, a_src, a_dst, Hs, as_, ad_, N, blockIdx.x, xs);
}

// ------- pass 1: multisplit edges into 196 dst-range bins (packed u32 = d<<16|s) -------
struct P1Smem {
    unsigned int stage[BATCH];
    int hist[NBINS];
    int off[NBINS];
    unsigned int gbase[NBINS];
    int total;
};

__device__ __forceinline__ void fill_pass1(const int* __restrict__ src,
                                           const int* __restrict__ dst,
                                           unsigned int* __restrict__ bin_cursor,
                                           unsigned int* __restrict__ bin_buf,
                                           int E, int bid, void* smem_raw) {
    P1Smem& S = *reinterpret_cast<P1Smem*>(smem_raw);
    const int tid = threadIdx.x;
    const int nbatch = (E + BATCH - 1) / BATCH;
    for (int b = bid; b < nbatch; b += P1_BLOCKS) {
        __syncthreads();
        for (int i = tid; i < NBINS; i += 256) S.hist[i] = 0;
        const int e0 = b * BATCH;
        unsigned int pk[8];
        int rk[8];
        bool ok[8];
#pragma unroll
        for (int k = 0; k < 8; ++k) {
            int e = e0 + tid + k * 256;
            ok[k] = (e < E);
            int d = ok[k] ? dst[e] : 0;
            int s = ok[k] ? src[e] : 0;
            pk[k] = ((unsigned)d << 16) | (unsigned)s;
            rk[k] = 0;
        }
        __syncthreads();
#pragma unroll
        for (int k = 0; k < 8; ++k)
            if (ok[k]) rk[k] = atomicAdd(&S.hist[pk[k] >> 24], 1);
        __syncthreads();
        // parallel Hillis-Steele inclusive scan
        for (int i = tid; i < NBINS; i += 256) S.off[i] = S.hist[i];
        __syncthreads();
#pragma unroll
        for (int d = 1; d < 256; d <<= 1) {
            int v = 0;
            if (tid < NBINS && tid >= d) v = S.off[tid - d];
            __syncthreads();
            if (tid < NBINS) S.off[tid] += v;
            __syncthreads();
        }
        if (tid == NBINS - 1) S.total = S.off[NBINS - 1];
        __syncthreads();
        if (tid < NBINS) S.off[tid] -= S.hist[tid];  // exclusive
        __syncthreads();
        if (tid < NBINS && S.hist[tid] > 0)
            S.gbase[tid] = atomicAdd(&bin_cursor[tid], (unsigned)S.hist[tid]);
#pragma unroll
        for (int k = 0; k < 8; ++k)
            if (ok[k]) S.stage[S.off[pk[k] >> 24] + rk[k]] = pk[k];
        __syncthreads();
        const int tot = S.total;
        for (int i = tid; i < tot; i += 256) {
            unsigned int v = S.stage[i];
            int bn = v >> 24;
            unsigned int p = S.gbase[bn] + (unsigned)(i - S.off[bn]);
            if (p < CAP) bin_buf[(size_t)bn * CAP + p] = v;
        }
    }
}

// ------- fused layer-0 MFMA GEMM + pass-1 -------
__global__ __launch_bounds__(256) void gemm0_fill_kernel(
    const float* __restrict__ X, const _Float16* __restrict__ Wt0,
    const float* __restrict__ a_src, const float* __restrict__ a_dst,
    _Float16* __restrict__ Hs, float* __restrict__ as_, float* __restrict__ ad_, int N,
    const int* __restrict__ src, const int* __restrict__ dst,
    unsigned int* __restrict__ bin_cursor, unsigned int* __restrict__ bin_buf, int E) {
    __shared__ __align__(16) unsigned char smem[16384];  // union: P1Smem / xs
    if (blockIdx.x < P1_BLOCKS) {
        fill_pass1(src, dst, bin_cursor, bin_buf, E, blockIdx.x, smem);
        return;
    }
    mfma_gemm_body<128, float>(X, Wt0, a_src, a_dst, Hs, as_, ad_, N, blockIdx.x - P1_BLOCKS,
                               reinterpret_cast<_Float16*>(smem));
}

// ------- pass 2: per-bin bucket build in LDS, coalesced writeback -------
__global__ __launch_bounds__(256) void fill_pass2(const unsigned int* __restrict__ bin_cursor,
                                                  const unsigned int* __restrict__ bin_buf,
                                                  int* __restrict__ cursor,
                                                  unsigned short* __restrict__ col, int N) {
    __shared__ unsigned short bk[BIN_NODES][SLOTS];  // 32KB
    __shared__ int cnt[BIN_NODES];                   // 1KB
    const int b = blockIdx.x;
    const int tid = threadIdx.x;
    const int base = b * BIN_NODES;
    const int nn = min(BIN_NODES, N - base);
    if (nn <= 0) return;
    cnt[tid] = 0;
    __syncthreads();
    const int ec = min((int)bin_cursor[b], CAP);
    for (int i = tid; i < ec; i += 256) {
        unsigned int v = bin_buf[(size_t)b * CAP + i];
        int d = (int)(v >> 16) - base;
        int p = atomicAdd(&cnt[d], 1);
        if (p < SLOTS) bk[d][p] = (unsigned short)(v & 0xFFFFu);
    }
    __syncthreads();
    unsigned int* col32 = reinterpret_cast<unsigned int*>(col);
    const unsigned int* lds32 = reinterpret_cast<const unsigned int*>(&bk[0][0]);
    const int words = nn * (SLOTS / 2);
    for (int i = tid; i < words; i += 256)
        col32[(size_t)base * (SLOTS / 2) + i] = lds32[i];
    if (tid < nn) cursor[base + tid] = cnt[tid];
}

// ------- alpha: per-layer normalized softmax weights (ONE exp pass, wave/node) -------
// w[node][slot] = exp(leaky(as[src]+ad[node])) / denom (fp16); wself = self term.
// This removes ALL exp/as_ loads and cross-lane reduces from the sliced gather
// (R7 post-mortem: 148 ds_bpermute/node was the 88us regression).
__global__ __launch_bounds__(256) void alpha_kernel(const float* __restrict__ as_,
                                                    const float* __restrict__ ad_,
                                                    const int* __restrict__ cursor,
                                                    const unsigned short* __restrict__ col,
                                                    _Float16* __restrict__ wgt,
                                                    float* __restrict__ wself, int N) {
    const int node = blockIdx.x * 4 + (threadIdx.x >> 6);
    if (node >= N) return;
    const int l = threadIdx.x & 63;
    const int cnt = min(cursor[node], SLOTS);
    const float adn = ad_[node];
    float e = 0.f;
    if (l < cnt) {
        int s = col[(node << 6) + l];
        e = __expf(leaky(as_[s] + adn));
    }
    float d = e;
#pragma unroll
    for (int off = 1; off < 64; off <<= 1)
        d += __shfl_xor(d, off, 64);
    const float es = __expf(leaky(as_[node] + adn));
    const float inv = 1.f / (d + es);
    wgt[(node << 6) + l] = (_Float16)(e * inv);
    if (l == 0) wself[node] = es * inv;
}

// ------- sliced weighted gather: lane owns ONE channel, serial edge loop -------
// Block = 8 nodes x one 32-ch slice; wave = 2 nodes x 32 lanes. Zero shuffles,
// zero exp. s = bid & (S-1): 2 (S=4) / 4 (S=2) XCDs share a slice -> 3.2MB/XCD L2
// working set. Per edge-slice: one 64B H segment (same segment count as R6, now L2-hit).
template <int S, bool POOL>
__global__ __launch_bounds__(256) void wgather_kernel(const _Float16* __restrict__ Hs,
                                                      const _Float16* __restrict__ wgt,
                                                      const float* __restrict__ wself,
                                                      const int* __restrict__ cursor,
                                                      const unsigned short* __restrict__ col,
                                                      const float* __restrict__ bias,
                                                      _Float16* __restrict__ OUT,
                                                      const int* __restrict__ batch,
                                                      float* __restrict__ pool_out, int N) {
    constexpr int SH = (S == 4) ? 2 : 1;
    __shared__ float pbuf[8][32];
    __shared__ int pg[8];
    const int j = blockIdx.x;
    const int s = j & (S - 1);
    const int g = j >> SH;
    const int wv = threadIdx.x >> 6;
    const int l = threadIdx.x & 63;
    const int half = l >> 5;
    const int ch = l & 31;
    const int node = g * 8 + wv * 2 + half;   // N%8==0 -> always < N
    const int cnt = min(cursor[node], SLOTS);
    const int base = node << 6;
    const _Float16* Hsl = Hs + (size_t)s * N * 32 + ch;

    float acc = 0.f;
    int e = 0;
    for (; e + 3 < cnt; e += 4) {
        int s0 = col[base + e];
        int s1 = col[base + e + 1];
        int s2 = col[base + e + 2];
        int s3 = col[base + e + 3];
        float w0 = (float)wgt[base + e];
        float w1 = (float)wgt[base + e + 1];
        float w2 = (float)wgt[base + e + 2];
        float w3 = (float)wgt[base + e + 3];
        float h0 = (float)Hsl[(size_t)s0 * 32];
        float h1 = (float)Hsl[(size_t)s1 * 32];
        float h2 = (float)Hsl[(size_t)s2 * 32];
        float h3 = (float)Hsl[(size_t)s3 * 32];
        acc += w0 * h0 + w1 * h1;
        acc += w2 * h2 + w3 * h3;
    }
    for (; e < cnt; ++e) {
        int s0 = col[base + e];
        acc += (float)wgt[base + e] * (float)Hsl[(size_t)s0 * 32];
    }
    acc += wself[node] * (float)Hsl[(size_t)node * 32];

    float r = acc + bias[s * 32 + ch];
    if (!POOL) {
        r = fmaxf(r, 0.f);  // relu on layers 0/1
        OUT[(size_t)node * 128 + s * 32 + ch] = (_Float16)r;
    } else {
        pbuf[wv * 2 + half][ch] = r;
        if ((l & 31) == 0) pg[wv * 2 + half] = batch[node];
        __syncthreads();
        if (threadIdx.x < 32) {
            const int c = threadIdx.x;
            if (pg[0] == pg[7]) {  // batch sorted: common case, one atomic
                float t = 0.f;
#pragma unroll
                for (int w = 0; w < 8; ++w) t += pbuf[w][c];
                atomicAdd(&pool_out[pg[0] * 64 + s * 32 + c], t);
            } else {
#pragma unroll
                for (int w = 0; w < 8; ++w)
                    atomicAdd(&pool_out[pg[w] * 64 + s * 32 + c], pbuf[w][c]);
            }
        }
    }
}

extern "C" void kernel_launch(void* const* d_in, const int* in_sizes, int n_in,
                              void* d_out, int out_size, void* d_ws, size_t ws_size,
                              hipStream_t stream) {
    const float* x = (const float*)d_in[0];
    const int* edge_index = (const int*)d_in[1];
    const int* batch = (const int*)d_in[2];
    const float* W0 = (const float*)d_in[3];
    const float* as0 = (const float*)d_in[4];
    const float* ad0 = (const float*)d_in[5];
    const float* b0 = (const float*)d_in[6];
    const float* W1 = (const float*)d_in[7];
    const float* as1 = (const float*)d_in[8];
    const float* ad1 = (const float*)d_in[9];
    const float* b1 = (const float*)d_in[10];
    const float* W2 = (const float*)d_in[11];
    const float* as2 = (const float*)d_in[12];
    const float* ad2 = (const float*)d_in[13];
    const float* b2 = (const float*)d_in[14];

    const int* e_src = edge_index;            // row 0
    const int* e_dst = edge_index + N_EDGES;  // row 1

    // workspace layout (byte-based; every region 16B-aligned)
    char* p = (char*)d_ws;
    _Float16* X16 = (_Float16*)p;     p += (size_t)N_NODES * 128 * 2;   // 12.8MB fp16 intermediate
    _Float16* Hs = (_Float16*)p;      p += (size_t)N_NODES * 128 * 2;   // 12.8MB slice-major H
    float* as_ = (float*)p;           p += (size_t)N_NODES * 4;
    float* ad_ = (float*)p;           p += (size_t)N_NODES * 4;
    int* cursor = (int*)p;            p += (size_t)N_NODES * 4;
    float* wself = (float*)p;         p += (size_t)N_NODES * 4;
    unsigned short* col = (unsigned short*)p; p += (size_t)N_NODES * SLOTS * 2;  // 6.4MB
    _Float16* wgt = (_Float16*)p;     p += (size_t)N_NODES * SLOTS * 2;          // 6.4MB
    unsigned int* bin_cursor = (unsigned int*)p; p += (size_t)((NBINS + 3) & ~3) * 4;
    unsigned int* bin_buf = (unsigned int*)p; p += (size_t)NBINS * CAP * 4;      // 4.8MB
    _Float16* Wt0 = (_Float16*)p;     p += (size_t)16384 * 2;
    _Float16* Wt1 = (_Float16*)p;     p += (size_t)16384 * 2;
    _Float16* Wt2 = (_Float16*)p;     p += (size_t)8192 * 2;

    const int GEMM_BLOCKS = (N_NODES + 63) / 64;
    const int ALPHA_BLOCKS = (N_NODES + 3) / 4;
    const int WG4_BLOCKS = (N_NODES / 8) * 4;   // 6250 groups x S=4 = 25000
    const int WG2_BLOCKS = (N_NODES / 8) * 2;   // 6250 groups x S=2 = 12500

    // ---- prep: W fragments + bin_cursor zero + d_out zero ----
    prep_kernel<<<20, 256, 0, stream>>>(W0, W1, W2, Wt0, Wt1, Wt2, bin_cursor,
                                        (float*)d_out, out_size);

    // ---- layer 0: MFMA gemm fused with fill pass-1 ----
    gemm0_fill_kernel<<<P1_BLOCKS + GEMM_BLOCKS, 256, 0, stream>>>(
        x, Wt0, as0, ad0, Hs, as_, ad_, N_NODES, e_src, e_dst, bin_cursor, bin_buf, N_EDGES);
    fill_pass2<<<NBINS, 256, 0, stream>>>(bin_cursor, bin_buf, cursor, col, N_NODES);
    alpha_kernel<<<ALPHA_BLOCKS, 256, 0, stream>>>(as_, ad_, cursor, col, wgt, wself, N_NODES);
    wgather_kernel<4, false><<<WG4_BLOCKS, 256, 0, stream>>>(
        Hs, wgt, wself, cursor, col, b0, X16, batch, nullptr, N_NODES);

    // ---- layer 1 ----
    mfma_gemm_kernel<128, _Float16><<<GEMM_BLOCKS, 256, 0, stream>>>(
        X16, Wt1, as1, ad1, Hs, as_, ad_, N_NODES);
    alpha_kernel<<<ALPHA_BLOCKS, 256, 0, stream>>>(as_, ad_, cursor, col, wgt, wself, N_NODES);
    wgather_kernel<4, false><<<WG4_BLOCKS, 256, 0, stream>>>(
        Hs, wgt, wself, cursor, col, b1, X16, batch, nullptr, N_NODES);

    // ---- layer 2 (64-wide = 2 slices), gather fused with pool ----
    mfma_gemm_kernel<64, _Float16><<<GEMM_BLOCKS, 256, 0, stream>>>(
        X16, Wt2, as2, ad2, Hs, as_, ad_, N_NODES);
    alpha_kernel<<<ALPHA_BLOCKS, 256, 0, stream>>>(as_, ad_, cursor, col, wgt, wself, N_NODES);
    wgather_kernel<2, true><<<WG2_BLOCKS, 256, 0, stream>>>(
        Hs, wgt, wself, cursor, col, b2, nullptr, batch, (float*)d_out, N_NODES);
}

// Round 9
// 250.605 us; speedup vs baseline: 1.4721x; 1.4721x over previous
//
#include <hip/hip_runtime.h>
#include <hip/hip_fp16.h>
#include <math.h>

#define N_NODES 50000
#define N_EDGES 800000
#define N_GRAPHS 64
#define NEG_SLOPE 0.2f
#define SLOTS 64        // bucket capacity; P(in-degree>64) ~ 1e-20 for Poisson(16)

// ---- multisplit fill parameters ----
#define BIN_NODES 256                   // nodes per dst-range bin
#define NBINS 196                       // ceil(50000/256)
#define CAP 6144                        // u32 slots per bin (mean 4082, sigma ~64)
#define P1_BLOCKS 192                   // pass-1 blocks fused ahead of gemm0
#define BATCH 2048                      // edges per block-batch (8 per thread)

typedef _Float16 f16x8 __attribute__((ext_vector_type(8)));
typedef float f32x4 __attribute__((ext_vector_type(4)));

__device__ __forceinline__ float leaky(float x) {
    return x > 0.f ? x : NEG_SLOPE * x;
}

// 16-byte chunk of 8 fp16 values (gather load/store granule)
struct __align__(16) half8 {
    __half2 h[4];
};

// ------- prep: W -> MFMA lane-major fp16 fragments; zero bin_cursor + d_out -------
// Wt layout: [kt][ct][lane][8] halves; lane l supplies B[k=kt*32+(l>>4)*8+b][c=ct*16+(l&15)].
__global__ __launch_bounds__(256) void prep_kernel(const float* __restrict__ W0,
                                                   const float* __restrict__ W1,
                                                   const float* __restrict__ W2,
                                                   _Float16* __restrict__ Wt0,
                                                   _Float16* __restrict__ Wt1,
                                                   _Float16* __restrict__ Wt2,
                                                   unsigned int* __restrict__ bin_cursor,
                                                   float* __restrict__ dout, int osz) {
    const int t = blockIdx.x * 256 + threadIdx.x;
    if (t < NBINS) bin_cursor[t] = 0;
    if (t < osz) dout[t] = 0.f;  // replaces the separate hipMemsetAsync dispatch
    const float* W;
    _Float16* Wt;
    int g, CTl, DOUTl;
    if (t < 2048) { W = W0; Wt = Wt0; g = t; CTl = 8; DOUTl = 128; }
    else if (t < 4096) { W = W1; Wt = Wt1; g = t - 2048; CTl = 8; DOUTl = 128; }
    else if (t < 5120) { W = W2; Wt = Wt2; g = t - 4096; CTl = 4; DOUTl = 64; }
    else return;
    const int kt = g / (CTl * 64);
    const int rem = g % (CTl * 64);
    const int ct = rem / 64;
    const int lane = rem % 64;
    const int kbase = kt * 32 + (lane >> 4) * 8;
    const int c = ct * 16 + (lane & 15);
#pragma unroll
    for (int b = 0; b < 8; ++b)
        Wt[(size_t)g * 8 + b] = (_Float16)W[(size_t)(kbase + b) * DOUTl + c];
}

// ------- MFMA GEMM body: H(fp16) = X @ W; as_ = h@a_src, ad_ = h@a_dst -------
// Block = 64 rows x DOUT cols, 4 waves x 16 rows. K=128 via 4x mfma_f32_16x16x32_f16.
// xs: 64x128 fp16 in LDS, 16B-chunk XOR swizzle (q ^ (row&15)) -> conflict-free A reads.
// XT = float (layer 0 input) or _Float16 (X written fp16 by the previous gather).
template <int DOUT, typename XT>
__device__ __forceinline__ void mfma_gemm_body(const XT* __restrict__ X,
                                               const _Float16* __restrict__ Wt,
                                               const float* __restrict__ a_src,
                                               const float* __restrict__ a_dst,
                                               _Float16* __restrict__ H,
                                               float* __restrict__ as_,
                                               float* __restrict__ ad_, int N, int bid,
                                               _Float16* xs) {
    constexpr int CT = DOUT / 16;
    const int tid = threadIdx.x;
    const int n0 = bid * 64;

    if constexpr (sizeof(XT) == 4) {
        const float4* X4 = reinterpret_cast<const float4*>(X);
        for (int idx = tid; idx < 64 * 16; idx += 256) {
            const int r = idx >> 4, q = idx & 15;
            const int n = n0 + r;
            float4 v0 = make_float4(0.f, 0.f, 0.f, 0.f), v1 = v0;
            if (n < N) {
                v0 = X4[(size_t)n * 32 + 2 * q];
                v1 = X4[(size_t)n * 32 + 2 * q + 1];
            }
            f16x8 hv;
            hv[0] = (_Float16)v0.x; hv[1] = (_Float16)v0.y;
            hv[2] = (_Float16)v0.z; hv[3] = (_Float16)v0.w;
            hv[4] = (_Float16)v1.x; hv[5] = (_Float16)v1.y;
            hv[6] = (_Float16)v1.z; hv[7] = (_Float16)v1.w;
            *reinterpret_cast<f16x8*>(&xs[r * 128 + ((q ^ (r & 15)) << 3)]) = hv;
        }
    } else {
        const f16x8* X8 = reinterpret_cast<const f16x8*>(X);
        for (int idx = tid; idx < 64 * 16; idx += 256) {
            const int r = idx >> 4, q = idx & 15;
            const int n = n0 + r;
            f16x8 hv = {};
            if (n < N) hv = X8[(size_t)n * 16 + q];
            *reinterpret_cast<f16x8*>(&xs[r * 128 + ((q ^ (r & 15)) << 3)]) = hv;
        }
    }
    __syncthreads();

    const int wave = tid >> 6, lane = tid & 63;
    const int colb = lane & 15;   // col within 16-tile; also A-row within wave tile
    const int kg = lane >> 4;     // k-group 0..3 (A); row-group (C/D)
    const int arow = wave * 16 + colb;

    f32x4 acc[CT];
#pragma unroll
    for (int ct = 0; ct < CT; ++ct) {
        acc[ct][0] = 0.f; acc[ct][1] = 0.f; acc[ct][2] = 0.f; acc[ct][3] = 0.f;
    }
    const f16x8* Wt8 = reinterpret_cast<const f16x8*>(Wt);
#pragma unroll
    for (int kt = 0; kt < 4; ++kt) {
        f16x8 A = *reinterpret_cast<const f16x8*>(
            &xs[arow * 128 + (((kt * 4 + kg) ^ (arow & 15)) << 3)]);
#pragma unroll
        for (int ct = 0; ct < CT; ++ct) {
            f16x8 B = Wt8[(kt * CT + ct) * 64 + lane];
            acc[ct] = __builtin_amdgcn_mfma_f32_16x16x32_f16(A, B, acc[ct], 0, 0, 0);
        }
    }

    // epilogue: H store (fp16) + alpha partials from f32 accs
    float ps[4] = {0.f, 0.f, 0.f, 0.f}, pd[4] = {0.f, 0.f, 0.f, 0.f};
#pragma unroll
    for (int ct = 0; ct < CT; ++ct) {
        const int col = ct * 16 + colb;
        const float asv = a_src[col];
        const float adv = a_dst[col];
#pragma unroll
        for (int r = 0; r < 4; ++r) {
            const float d = acc[ct][r];
            ps[r] += d * asv;
            pd[r] += d * adv;
            const int row = n0 + wave * 16 + kg * 4 + r;
            if (row < N) H[(size_t)row * DOUT + col] = (_Float16)d;
        }
    }
#pragma unroll
    for (int off = 1; off < 16; off <<= 1) {
#pragma unroll
        for (int r = 0; r < 4; ++r) {
            ps[r] += __shfl_xor(ps[r], off, 64);
            pd[r] += __shfl_xor(pd[r], off, 64);
        }
    }
    if (colb == 0) {
#pragma unroll
        for (int r = 0; r < 4; ++r) {
            const int row = n0 + wave * 16 + kg * 4 + r;
            if (row < N) {
                as_[row] = ps[r];
                ad_[row] = pd[r];
            }
        }
    }
}

template <int DOUT, typename XT>
__global__ __launch_bounds__(256) void mfma_gemm_kernel(const XT* __restrict__ X,
                                                        const _Float16* __restrict__ Wt,
                                                        const float* __restrict__ a_src,
                                                        const float* __restrict__ a_dst,
                                                        _Float16* __restrict__ H,
                                                        float* __restrict__ as_,
                                                        float* __restrict__ ad_, int N) {
    __shared__ __align__(16) _Float16 xs[64 * 128];
    mfma_gemm_body<DOUT, XT>(X, Wt, a_src, a_dst, H, as_, ad_, N, blockIdx.x, xs);
}

// ------- pass 1: multisplit edges into 196 dst-range bins (packed u32 = d<<16|s) -------
struct P1Smem {
    unsigned int stage[BATCH];
    int hist[NBINS];
    int off[NBINS];
    unsigned int gbase[NBINS];
    int total;
};

__device__ __forceinline__ void fill_pass1(const int* __restrict__ src,
                                           const int* __restrict__ dst,
                                           unsigned int* __restrict__ bin_cursor,
                                           unsigned int* __restrict__ bin_buf,
                                           int E, int bid, void* smem_raw) {
    P1Smem& S = *reinterpret_cast<P1Smem*>(smem_raw);
    const int tid = threadIdx.x;
    const int nbatch = (E + BATCH - 1) / BATCH;
    for (int b = bid; b < nbatch; b += P1_BLOCKS) {
        __syncthreads();  // protect stage/hist reuse across batches
        for (int i = tid; i < NBINS; i += 256) S.hist[i] = 0;
        const int e0 = b * BATCH;
        unsigned int pk[8];
        int rk[8];
        bool ok[8];
#pragma unroll
        for (int k = 0; k < 8; ++k) {
            int e = e0 + tid + k * 256;
            ok[k] = (e < E);
            int d = ok[k] ? dst[e] : 0;
            int s = ok[k] ? src[e] : 0;
            pk[k] = ((unsigned)d << 16) | (unsigned)s;
            rk[k] = 0;
        }
        __syncthreads();
#pragma unroll
        for (int k = 0; k < 8; ++k)
            if (ok[k]) rk[k] = atomicAdd(&S.hist[pk[k] >> 24], 1);
        __syncthreads();
        // parallel Hillis-Steele inclusive scan (replaces tid0 serial 196-iter scan)
        for (int i = tid; i < NBINS; i += 256) S.off[i] = S.hist[i];
        __syncthreads();
#pragma unroll
        for (int d = 1; d < 256; d <<= 1) {
            int v = 0;
            if (tid < NBINS && tid >= d) v = S.off[tid - d];
            __syncthreads();
            if (tid < NBINS) S.off[tid] += v;
            __syncthreads();
        }
        if (tid == NBINS - 1) S.total = S.off[NBINS - 1];
        __syncthreads();
        if (tid < NBINS) S.off[tid] -= S.hist[tid];  // exclusive
        __syncthreads();
        if (tid < NBINS && S.hist[tid] > 0)
            S.gbase[tid] = atomicAdd(&bin_cursor[tid], (unsigned)S.hist[tid]);
#pragma unroll
        for (int k = 0; k < 8; ++k)
            if (ok[k]) S.stage[S.off[pk[k] >> 24] + rk[k]] = pk[k];
        __syncthreads();
        const int tot = S.total;
        for (int i = tid; i < tot; i += 256) {
            unsigned int v = S.stage[i];
            int bn = v >> 24;
            unsigned int p = S.gbase[bn] + (unsigned)(i - S.off[bn]);
            if (p < CAP) bin_buf[(size_t)bn * CAP + p] = v;
        }
    }
}

// ------- fused layer-0 MFMA GEMM + pass-1 (independent dataflow -> overlap) -------
__global__ __launch_bounds__(256) void gemm0_fill_kernel(
    const float* __restrict__ X, const _Float16* __restrict__ Wt0,
    const float* __restrict__ a_src, const float* __restrict__ a_dst,
    _Float16* __restrict__ H, float* __restrict__ as_, float* __restrict__ ad_, int N,
    const int* __restrict__ src, const int* __restrict__ dst,
    unsigned int* __restrict__ bin_cursor, unsigned int* __restrict__ bin_buf, int E) {
    __shared__ __align__(16) unsigned char smem[16384];  // union: P1Smem (10.5KB) / xs (16KB)
    if (blockIdx.x < P1_BLOCKS) {
        fill_pass1(src, dst, bin_cursor, bin_buf, E, blockIdx.x, smem);
        return;
    }
    mfma_gemm_body<128, float>(X, Wt0, a_src, a_dst, H, as_, ad_, N, blockIdx.x - P1_BLOCKS,
                               reinterpret_cast<_Float16*>(smem));
}

// ------- pass 2: per-bin bucket build in LDS, coalesced writeback -------
__global__ __launch_bounds__(256) void fill_pass2(const unsigned int* __restrict__ bin_cursor,
                                                  const unsigned int* __restrict__ bin_buf,
                                                  int* __restrict__ cursor,
                                                  unsigned short* __restrict__ col, int N) {
    __shared__ unsigned short bk[BIN_NODES][SLOTS];  // 32KB
    __shared__ int cnt[BIN_NODES];                   // 1KB
    const int b = blockIdx.x;
    const int tid = threadIdx.x;
    const int base = b * BIN_NODES;
    const int nn = min(BIN_NODES, N - base);
    if (nn <= 0) return;
    cnt[tid] = 0;
    __syncthreads();
    const int ec = min((int)bin_cursor[b], CAP);
    for (int i = tid; i < ec; i += 256) {
        unsigned int v = bin_buf[(size_t)b * CAP + i];
        int d = (int)(v >> 16) - base;  // in [0, BIN_NODES)
        int p = atomicAdd(&cnt[d], 1);
        if (p < SLOTS) bk[d][p] = (unsigned short)(v & 0xFFFFu);
    }
    __syncthreads();
    unsigned int* col32 = reinterpret_cast<unsigned int*>(col);
    const unsigned int* lds32 = reinterpret_cast<const unsigned int*>(&bk[0][0]);
    const int words = nn * (SLOTS / 2);
    for (int i = tid; i < words; i += 256)
        col32[(size_t)base * (SLOTS / 2) + i] = lds32[i];
    if (tid < nn) cursor[base + tid] = cnt[tid];
}

// ------- fused softmax + gather per dst node (wave per node, no max pass) -------
// H fp16; 16B loads (NCH = DOUT/8 lanes per edge). POOL=false: fp16 OUT + relu
// (feeds next gemm). POOL=true (layer 2): block-reduce 4 rows in LDS and
// atomicAdd into d_out (pool_kernel + its 25MB round-trip + memset eliminated).
template <int DOUT, bool POOL>
__global__ __launch_bounds__(256) void gather_kernel(const half8* __restrict__ H8,
                                                     const float* __restrict__ as_,
                                                     const float* __restrict__ ad_,
                                                     const int* __restrict__ cursor,
                                                     const unsigned short* __restrict__ col,
                                                     const float* __restrict__ bias,
                                                     half8* __restrict__ OUT,
                                                     const int* __restrict__ batch,
                                                     float* __restrict__ pool_out, int N) {
    constexpr int NCH = DOUT / 8;   // lanes per edge: 16 or 8
    constexpr int SUBS = 64 / NCH;  // subgroups: 4 or 8
    __shared__ float pbuf[4][64];
    __shared__ int pg[4];
    const int wv = threadIdx.x >> 6;
    const int node = blockIdx.x * 4 + wv;
    if (!POOL && node >= N) return;  // N%4==0: never fires, kept for safety
    const int l = threadIdx.x & 63;
    const int ch = l & (NCH - 1);
    const int sub = l / NCH;

    const float adn = ad_[node];
    const float sl = leaky(as_[node] + adn);
    const int rs = node << 6;
    const int re = rs + min(cursor[node], SLOTS);

    float acc[8] = {};
    float dsum = 0.f;

    int i = rs + sub;
    for (; i + 3 * SUBS < re; i += 4 * SUBS) {
        int s[4];
        float a[4];
        half8 h[4];
#pragma unroll
        for (int u = 0; u < 4; ++u) s[u] = col[i + u * SUBS];
#pragma unroll
        for (int u = 0; u < 4; ++u) a[u] = as_[s[u]];
#pragma unroll
        for (int u = 0; u < 4; ++u) h[u] = H8[(size_t)s[u] * NCH + ch];
#pragma unroll
        for (int u = 0; u < 4; ++u) {
            float ee = __expf(leaky(a[u] + adn));
#pragma unroll
            for (int j = 0; j < 4; ++j) {
                float2 f = __half22float2(h[u].h[j]);
                acc[2 * j] += ee * f.x;
                acc[2 * j + 1] += ee * f.y;
            }
            dsum += ee;
        }
    }
    for (; i + SUBS < re; i += 2 * SUBS) {
        int s0 = col[i], s1 = col[i + SUBS];
        float a0 = as_[s0], a1 = as_[s1];
        half8 h0 = H8[(size_t)s0 * NCH + ch];
        half8 h1 = H8[(size_t)s1 * NCH + ch];
        float e0 = __expf(leaky(a0 + adn));
        float e1 = __expf(leaky(a1 + adn));
#pragma unroll
        for (int j = 0; j < 4; ++j) {
            float2 f0 = __half22float2(h0.h[j]);
            float2 f1 = __half22float2(h1.h[j]);
            acc[2 * j] += e0 * f0.x + e1 * f1.x;
            acc[2 * j + 1] += e0 * f0.y + e1 * f1.y;
        }
        dsum += e0 + e1;
    }
    if (i < re) {
        int s0 = col[i];
        float e0 = __expf(leaky(as_[s0] + adn));
        half8 h0 = H8[(size_t)s0 * NCH + ch];
#pragma unroll
        for (int j = 0; j < 4; ++j) {
            float2 f = __half22float2(h0.h[j]);
            acc[2 * j] += e0 * f.x;
            acc[2 * j + 1] += e0 * f.y;
        }
        dsum += e0;
    }

    // dsum identical across a subgroup's NCH lanes; combine subgroups only
#pragma unroll
    for (int off = 32; off >= NCH; off >>= 1)
        dsum += __shfl_xor(dsum, off, 64);
#pragma unroll
    for (int off = 32; off >= NCH; off >>= 1) {
#pragma unroll
        for (int j = 0; j < 8; ++j)
            acc[j] += __shfl_down(acc[j], off, 64);
    }

    if (l < NCH) {
        const float e_self = __expf(sl);
        half8 h = H8[(size_t)node * NCH + ch];
        const float inv_pre = dsum + e_self;
        const float inv = 1.f / inv_pre;
        const float4* b4 = reinterpret_cast<const float4*>(bias);
        const float4 ba = b4[2 * ch], bb = b4[2 * ch + 1];
        const float bj[8] = {ba.x, ba.y, ba.z, ba.w, bb.x, bb.y, bb.z, bb.w};
        float r[8];
#pragma unroll
        for (int j = 0; j < 4; ++j) {
            float2 f = __half22float2(h.h[j]);
            acc[2 * j] += e_self * f.x;
            acc[2 * j + 1] += e_self * f.y;
        }
#pragma unroll
        for (int j = 0; j < 8; ++j) {
            r[j] = acc[j] * inv + bj[j];
            if (!POOL) r[j] = fmaxf(r[j], 0.f);  // relu on layers 0/1 only
        }
        if (POOL) {
#pragma unroll
            for (int j = 0; j < 8; ++j) pbuf[wv][ch * 8 + j] = r[j];
        } else {
            half8 o;
#pragma unroll
            for (int j = 0; j < 4; ++j)
                o.h[j] = __floats2half2_rn(r[2 * j], r[2 * j + 1]);
            OUT[(size_t)node * NCH + ch] = o;
        }
    }
    if (POOL) {
        if (l == 0) pg[wv] = batch[node];
        __syncthreads();
        if (threadIdx.x < 64) {
            const int c = threadIdx.x;
            const int g0 = pg[0], g3 = pg[3];
            if (g0 == g3) {  // batch sorted: g0==g3 => all four equal (common case)
                atomicAdd(&pool_out[g0 * 64 + c],
                          pbuf[0][c] + pbuf[1][c] + pbuf[2][c] + pbuf[3][c]);
            } else {
#pragma unroll
                for (int w = 0; w < 4; ++w)
                    atomicAdd(&pool_out[pg[w] * 64 + c], pbuf[w][c]);
            }
        }
    }
}

extern "C" void kernel_launch(void* const* d_in, const int* in_sizes, int n_in,
                              void* d_out, int out_size, void* d_ws, size_t ws_size,
                              hipStream_t stream) {
    const float* x = (const float*)d_in[0];
    const int* edge_index = (const int*)d_in[1];
    const int* batch = (const int*)d_in[2];
    const float* W0 = (const float*)d_in[3];
    const float* as0 = (const float*)d_in[4];
    const float* ad0 = (const float*)d_in[5];
    const float* b0 = (const float*)d_in[6];
    const float* W1 = (const float*)d_in[7];
    const float* as1 = (const float*)d_in[8];
    const float* ad1 = (const float*)d_in[9];
    const float* b1 = (const float*)d_in[10];
    const float* W2 = (const float*)d_in[11];
    const float* as2 = (const float*)d_in[12];
    const float* ad2 = (const float*)d_in[13];
    const float* b2 = (const float*)d_in[14];

    const int* e_src = edge_index;            // row 0
    const int* e_dst = edge_index + N_EDGES;  // row 1

    // workspace layout (byte-based; every region 16B-aligned)
    char* p = (char*)d_ws;
    _Float16* X16 = (_Float16*)p;     p += (size_t)N_NODES * 128 * 2;   // 12.8MB fp16 intermediate
    _Float16* H = (_Float16*)p;       p += (size_t)N_NODES * 128 * 2;   // 12.8MB
    float* as_ = (float*)p;           p += (size_t)N_NODES * 4;
    float* ad_ = (float*)p;           p += (size_t)N_NODES * 4;
    int* cursor = (int*)p;            p += (size_t)N_NODES * 4;
    unsigned short* col = (unsigned short*)p; p += (size_t)N_NODES * SLOTS * 2;  // 6.4MB
    unsigned int* bin_cursor = (unsigned int*)p; p += (size_t)((NBINS + 3) & ~3) * 4;
    unsigned int* bin_buf = (unsigned int*)p; p += (size_t)NBINS * CAP * 4;      // 4.8MB
    _Float16* Wt0 = (_Float16*)p;     p += (size_t)16384 * 2;
    _Float16* Wt1 = (_Float16*)p;     p += (size_t)16384 * 2;
    _Float16* Wt2 = (_Float16*)p;     p += (size_t)8192 * 2;

    const int NODE_BLOCKS = (N_NODES + 3) / 4;
    const int GEMM_BLOCKS = (N_NODES + 63) / 64;

    // ---- prep: W fragments + bin_cursor zero + d_out zero ----
    prep_kernel<<<20, 256, 0, stream>>>(W0, W1, W2, Wt0, Wt1, Wt2, bin_cursor,
                                        (float*)d_out, out_size);

    // ---- layer 0 MFMA gemm fused with fill pass-1 (independent -> overlap) ----
    gemm0_fill_kernel<<<P1_BLOCKS + GEMM_BLOCKS, 256, 0, stream>>>(
        x, Wt0, as0, ad0, H, as_, ad_, N_NODES, e_src, e_dst, bin_cursor, bin_buf, N_EDGES);
    fill_pass2<<<NBINS, 256, 0, stream>>>(bin_cursor, bin_buf, cursor, col, N_NODES);
    gather_kernel<128, false><<<NODE_BLOCKS, 256, 0, stream>>>(
        (const half8*)H, as_, ad_, cursor, col, b0, (half8*)X16, batch, nullptr, N_NODES);

    // ---- layer 1: X16 -> H (relu inside gather) ----
    mfma_gemm_kernel<128, _Float16><<<GEMM_BLOCKS, 256, 0, stream>>>(
        X16, Wt1, as1, ad1, H, as_, ad_, N_NODES);
    gather_kernel<128, false><<<NODE_BLOCKS, 256, 0, stream>>>(
        (const half8*)H, as_, ad_, cursor, col, b1, (half8*)X16, batch, nullptr, N_NODES);

    // ---- layer 2: X16 -> H (64-wide), gather fused with global add pool ----
    mfma_gemm_kernel<64, _Float16><<<GEMM_BLOCKS, 256, 0, stream>>>(
        X16, Wt2, as2, ad2, H, as_, ad_, N_NODES);
    gather_kernel<64, true><<<NODE_BLOCKS, 256, 0, stream>>>(
        (const half8*)H, as_, ad_, cursor, col, b2, nullptr, batch, (float*)d_out, N_NODES);
}